// Round 1
// baseline (621.428 us; speedup 1.0000x reference)
//
#include <hip/hip_runtime.h>
#include <hip/hip_fp16.h>

// DepTreeLSTM on MI355X.
// Structure (from reference _structure()): each pair p owns nodes p*16+pos,
// pos 0..15; edges point toward ROOT=8. level_up(pos)= pos<=8?pos:15-pos,
// level_down(pos)=|pos-8|. We hard-code this deterministic pattern.
//
// Per (direction, level) we run ONE fused MFMA GEMM:
//   A row = [ x_node (320, gathered fp32->fp16) || h_src (64, fp16 state) ]
//   B     = [ [W_iou | W_f] ; [U_iou | U_f] ]  (384 x 256, fp16, packed)
//   C row = preacts [i(64) o(64) u(64) f(64)]  (fp32 accum)
// Epilogue does the LSTM cell update in-register (wave n-split chosen so each
// lane owns matching i/o/u/f columns) and writes h,c (fp16) to ws state, or
// the final h to d_out.
// Root (up, level 8) uses 4 rows/pair: [x||h7],[x||h9],[x||0],[0||0];
// iou = r0+r1-r2, f7 = r0.f, f9 = r1.f.

typedef _Float16 f16x8 __attribute__((ext_vector_type(8)));
typedef float f32x4 __attribute__((ext_vector_type(4)));

#define T_ 512

__global__ __launch_bounds__(256) void pack_weights(
    const float* __restrict__ Wi_u, const float* __restrict__ Ui_u,
    const float* __restrict__ Wf_u, const float* __restrict__ Uf_u,
    const float* __restrict__ Wi_d, const float* __restrict__ Ui_d,
    const float* __restrict__ Wf_d, const float* __restrict__ Uf_d,
    _Float16* __restrict__ Bt)   // layout [dir][col(256)][k(384)]
{
    int idx = blockIdx.x * 256 + threadIdx.x;   // 2*256*384 = 196608 total
    int d   = idx / 98304;
    int rem = idx % 98304;
    int col = rem / 384;
    int k   = rem % 384;
    const float* Wi = d ? Wi_d : Wi_u;
    const float* Ui = d ? Ui_d : Ui_u;
    const float* Wf = d ? Wf_d : Wf_u;
    const float* Uf = d ? Uf_d : Uf_u;
    float v;
    if (col < 192) v = (k < 320) ? Wi[k * 192 + col] : Ui[(k - 320) * 192 + col];
    else {
        int c = col - 192;
        v = (k < 320) ? Wf[k * 64 + c] : Uf[(k - 320) * 64 + c];
    }
    Bt[idx] = (_Float16)v;
}

__device__ __forceinline__ float sigm(float x) { return 1.f / (1.f + __expf(-x)); }

__global__ __launch_bounds__(256) void level_kernel(
    const float* __restrict__ tok, const float* __restrict__ oh,
    const float* __restrict__ dep,
    const int* __restrict__ nb, const int* __restrict__ nt,
    const _Float16* __restrict__ Bt,          // this direction's 256x384 fp16
    const float* __restrict__ b_iou, const float* __restrict__ b_f,
    _Float16* __restrict__ h_st, _Float16* __restrict__ c_st,
    float* __restrict__ out,
    int rp_shift, int is_root,
    int4 pos, int4 hpos, int4 ocol)
{
    __shared__ _Float16 At[64 * 40];     // A tile 64 rows x 32 k, stride 40
    __shared__ _Float16 Btl[256 * 40];   // B tile 256 cols x 32 k, stride 40
    __shared__ int ld_b[64], ld_t[64], ld_hn[64];

    const int tid  = threadIdx.x;
    const int lane = tid & 63;
    const int w    = tid >> 6;
    const int rp_mask = (1 << rp_shift) - 1;

    if (tid < 64) {
        int grow = blockIdx.x * 64 + tid;
        int pair = grow >> rp_shift;
        int slot = grow & rp_mask;
        int ps = (slot == 0) ? pos.x : (slot == 1) ? pos.y : (slot == 2) ? pos.z : pos.w;
        int hp = (slot == 0) ? hpos.x : (slot == 1) ? hpos.y : (slot == 2) ? hpos.z : hpos.w;
        int zero_x = (is_root && slot == 3);
        int node = pair * 16 + ps;
        ld_b[tid]  = zero_x ? -1 : nb[node];
        ld_t[tid]  = zero_x ? 0  : nt[node];
        ld_hn[tid] = (hp < 0) ? -1 : pair * 16 + hp;
    }
    __syncthreads();

    f32x4 acc[4][4];
    for (int i = 0; i < 4; ++i)
        for (int j = 0; j < 4; ++j)
            acc[i][j] = (f32x4){0.f, 0.f, 0.f, 0.f};

    const int rr = tid >> 2, q = tid & 3;
    const int l15 = lane & 15, qd = lane >> 4;

    for (int kt = 0; kt < 12; ++kt) {
        const int k0 = kt * 32;
        // ---- stage A tile (64 x 32 fp16) ----
        f16x8 av;
        if (kt < 10) {
            int b = ld_b[rr];
            if (b < 0) {
                for (int e = 0; e < 8; ++e) av[e] = (_Float16)0.f;
            } else {
                int t = ld_t[rr];
                int kk = k0 + q * 8;
                const float* src;
                size_t bt = (size_t)b * T_ + t;
                if (kk < 256)      src = tok + bt * 256 + kk;
                else if (kk < 288) src = oh  + bt * 32  + (kk - 256);
                else               src = dep + bt * 32  + (kk - 288);
                float4 f0 = *(const float4*)src;
                float4 f1 = *(const float4*)(src + 4);
                av[0] = (_Float16)f0.x; av[1] = (_Float16)f0.y;
                av[2] = (_Float16)f0.z; av[3] = (_Float16)f0.w;
                av[4] = (_Float16)f1.x; av[5] = (_Float16)f1.y;
                av[6] = (_Float16)f1.z; av[7] = (_Float16)f1.w;
            }
        } else {
            int hn = ld_hn[rr];
            if (hn < 0) {
                for (int e = 0; e < 8; ++e) av[e] = (_Float16)0.f;
            } else {
                av = *(const f16x8*)(h_st + (size_t)hn * 64 + (kt - 10) * 32 + q * 8);
            }
        }
        *(f16x8*)&At[rr * 40 + q * 8] = av;

        // ---- stage B tile (256 cols x 32 k fp16), Bt is [col][k] ----
        for (int pass = 0; pass < 4; ++pass) {
            int c = pass * 64 + rr;
            f16x8 bv = *(const f16x8*)(Bt + (size_t)c * 384 + k0 + q * 8);
            *(f16x8*)&Btl[c * 40 + q * 8] = bv;
        }
        __syncthreads();

        // ---- MFMA: block M=64, this wave covers cols {j*64 + w*16 + 0..15} ----
        f16x8 af[4];
        for (int i = 0; i < 4; ++i)
            af[i] = *(const f16x8*)&At[(i * 16 + l15) * 40 + qd * 8];
        for (int j = 0; j < 4; ++j) {
            f16x8 bf8 = *(const f16x8*)&Btl[(j * 64 + w * 16 + l15) * 40 + qd * 8];
            for (int i = 0; i < 4; ++i)
                acc[i][j] = __builtin_amdgcn_mfma_f32_16x16x32_f16(af[i], bf8, acc[i][j], 0, 0, 0);
        }
        __syncthreads();
    }

    // ---- epilogue: lane owns matching i/o/u/f columns at colj = w*16+l15 ----
    const int colj = w * 16 + l15;
    const float bi = b_iou[colj], bo = b_iou[64 + colj],
                bu = b_iou[128 + colj], bff = b_f[colj];

    if (!is_root) {
        for (int i = 0; i < 4; ++i) {
            int lr_base = i * 16 + qd * 4;
            for (int r = 0; r < 4; ++r) {
                int lr = lr_base + r;
                int grow = blockIdx.x * 64 + lr;
                int pair = grow >> rp_shift;
                int slot = grow & rp_mask;
                float I = acc[i][0][r] + bi;
                float O = acc[i][1][r] + bo;
                float U = acc[i][2][r] + bu;
                float F = acc[i][3][r] + bff;
                int hn = ld_hn[lr];
                float cin = (hn >= 0) ? (float)c_st[(size_t)hn * 64 + colj] : 0.f;
                float cn = sigm(I) * tanhf(U) + sigm(F) * cin;
                float h  = sigm(O) * tanhf(cn);
                int oc = (slot == 0) ? ocol.x : (slot == 1) ? ocol.y
                       : (slot == 2) ? ocol.z : ocol.w;
                if (oc >= 0) {
                    out[(size_t)pair * 192 + oc + colj] = h;
                } else {
                    int ps = (slot == 0) ? pos.x : (slot == 1) ? pos.y
                           : (slot == 2) ? pos.z : pos.w;
                    size_t node = (size_t)(pair * 16 + ps) * 64 + colj;
                    h_st[node] = (_Float16)h;
                    c_st[node] = (_Float16)cn;
                }
            }
        }
    } else {
        // 4 rows/pair: r0=[x||h7], r1=[x||h9], r2=[x||0], r3=zeros
        for (int i = 0; i < 4; ++i) {
            int lr_base = i * 16 + qd * 4;
            int grow = blockIdx.x * 64 + lr_base;
            int pair = grow >> 2;
            float I  = acc[i][0][0] + acc[i][0][1] - acc[i][0][2] + bi;
            float O  = acc[i][1][0] + acc[i][1][1] - acc[i][1][2] + bo;
            float U  = acc[i][2][0] + acc[i][2][1] - acc[i][2][2] + bu;
            float F7 = acc[i][3][0] + bff;
            float F9 = acc[i][3][1] + bff;
            float c7 = (float)c_st[(size_t)(pair * 16 + 7) * 64 + colj];
            float c9 = (float)c_st[(size_t)(pair * 16 + 9) * 64 + colj];
            float fc = sigm(F7) * c7 + sigm(F9) * c9;
            float cn = sigm(I) * tanhf(U) + fc;
            float h  = sigm(O) * tanhf(cn);
            out[(size_t)pair * 192 + colj] = h;
        }
    }
}

extern "C" void kernel_launch(void* const* d_in, const int* in_sizes, int n_in,
                              void* d_out, int out_size, void* d_ws, size_t ws_size,
                              hipStream_t stream)
{
    const float* tok  = (const float*)d_in[0];
    const float* ohp  = (const float*)d_in[1];
    const float* dep  = (const float*)d_in[2];
    const int*   nb   = (const int*)d_in[3];
    const int*   nt   = (const int*)d_in[4];
    const float* Wi_u = (const float*)d_in[13];
    const float* Ui_u = (const float*)d_in[14];
    const float* bi_u = (const float*)d_in[15];
    const float* Wf_u = (const float*)d_in[16];
    const float* Uf_u = (const float*)d_in[17];
    const float* bf_u = (const float*)d_in[18];
    const float* Wi_d = (const float*)d_in[19];
    const float* Ui_d = (const float*)d_in[20];
    const float* bi_d = (const float*)d_in[21];
    const float* Wf_d = (const float*)d_in[22];
    const float* Uf_d = (const float*)d_in[23];
    const float* bf_d = (const float*)d_in[24];

    char* ws = (char*)d_ws;
    _Float16* Bt   = (_Float16*)ws;                              // 2*256*384*2 B
    _Float16* h_st = (_Float16*)(ws + (512 << 10));              // 33.5 MB
    _Float16* c_st = (_Float16*)(ws + (512 << 10) + (32 << 20)); // 33.5 MB
    float* out = (float*)d_out;

    pack_weights<<<768, 256, 0, stream>>>(Wi_u, Ui_u, Wf_u, Uf_u,
                                          Wi_d, Ui_d, Wf_d, Uf_d, Bt);

    const _Float16* Bu = Bt;
    const _Float16* Bd = Bt + 98304;

    // -------- upward pass --------
    for (int t = 0; t < 7; ++t) {   // 2 rows/pair: pos t (child t-1), pos 15-t (child 16-t)
        int4 pos = {t, 15 - t, 0, 0};
        int4 hp  = {t == 0 ? -1 : t - 1, t == 0 ? -1 : 16 - t, -1, -1};
        int4 oc  = {-1, -1, -1, -1};
        level_kernel<<<512, 256, 0, stream>>>(tok, ohp, dep, nb, nt, Bu, bi_u, bf_u,
                                              h_st, c_st, out, 1, 0, pos, hp, oc);
    }
    {   // level 7: pos 7 only
        int4 pos = {7, 0, 0, 0}, hp = {6, -1, -1, -1}, oc = {-1, -1, -1, -1};
        level_kernel<<<256, 256, 0, stream>>>(tok, ohp, dep, nb, nt, Bu, bi_u, bf_u,
                                              h_st, c_st, out, 0, 0, pos, hp, oc);
    }
    {   // level 8: root, 4 rows/pair, writes out cols 0..63
        int4 pos = {8, 8, 8, 8}, hp = {7, 9, -1, -1}, oc = {0, 0, 0, 0};
        level_kernel<<<1024, 256, 0, stream>>>(tok, ohp, dep, nb, nt, Bu, bi_u, bf_u,
                                               h_st, c_st, out, 2, 1, pos, hp, oc);
    }

    // -------- downward pass (reuses h_st/c_st; only reads what it wrote) ----
    {   // level 0: root, hp = 0
        int4 pos = {8, 0, 0, 0}, hp = {-1, -1, -1, -1}, oc = {-1, -1, -1, -1};
        level_kernel<<<256, 256, 0, stream>>>(tok, ohp, dep, nb, nt, Bd, bi_d, bf_d,
                                              h_st, c_st, out, 0, 0, pos, hp, oc);
    }
    for (int t = 1; t < 7; ++t) {   // pos 8-t (parent 9-t), pos 8+t (parent 7+t)
        int4 pos = {8 - t, 8 + t, 0, 0};
        int4 hp  = {9 - t, 7 + t, -1, -1};
        int4 oc  = {-1, -1, -1, -1};
        level_kernel<<<512, 256, 0, stream>>>(tok, ohp, dep, nb, nt, Bd, bi_d, bf_d,
                                              h_st, c_st, out, 1, 0, pos, hp, oc);
    }
    {   // level 7: pos 1 -> state, pos 15 -> out cols 128..191 (end_idx)
        int4 pos = {1, 15, 0, 0}, hp = {2, 14, -1, -1}, oc = {-1, 128, -1, -1};
        level_kernel<<<512, 256, 0, stream>>>(tok, ohp, dep, nb, nt, Bd, bi_d, bf_d,
                                              h_st, c_st, out, 1, 0, pos, hp, oc);
    }
    {   // level 8: pos 0 -> out cols 64..127 (start_idx)
        int4 pos = {0, 0, 0, 0}, hp = {1, -1, -1, -1}, oc = {64, -1, -1, -1};
        level_kernel<<<256, 256, 0, stream>>>(tok, ohp, dep, nb, nt, Bd, bi_d, bf_d,
                                              h_st, c_st, out, 0, 0, pos, hp, oc);
    }
    (void)in_sizes; (void)n_in; (void)out_size; (void)ws_size;
}

// Round 2
// 405.728 us; speedup vs baseline: 1.5316x; 1.5316x over previous
//
#include <hip/hip_runtime.h>
#include <hip/hip_fp16.h>
#include <stdint.h>

// DepTreeLSTM on MI355X — fused per-(direction,level) GEMM, K=384:
//   A row = [ x_node (320 fp16, pre-converted table) || h_src (64 fp16 state) ]
//   B     = [ [W_iou | W_f] ; [U_iou | U_f] ]  (384 x 256 fp16, [col][k])
// Block tile: M=128, N=256, BK=64 (6 k-tiles). Staging via
// global_load_lds width=16 with XOR-8 granule swizzle (conflict-free reads).
// Up and down passes use separate state buffers -> merged into one launch
// per level (block-range dispatch). Root = 4-row trick: [x||h7],[x||h9],
// [x||0],[0||0]; iou = r0+r1-r2, f7=r0.f, f9=r1.f.

typedef _Float16 f16x8 __attribute__((ext_vector_type(8)));
typedef float f32x4 __attribute__((ext_vector_type(4)));

struct Side {
    const _Float16* B;       // 256x384 packed weights, [col][k]
    const float* b_iou;      // 192 (i,o,u per 64)
    const float* b_f;        // 64
    _Float16* h;             // state [N][64]
    _Float16* c;             // state [N][64]
    int rp_shift;            // log2(rows per pair)
    int is_root;
    int4 pos, hpos, ocol;
};

__device__ __forceinline__ void async16(const void* g, void* l) {
    __builtin_amdgcn_global_load_lds(
        (const __attribute__((address_space(1))) void*)g,
        (__attribute__((address_space(3))) void*)l, 16, 0, 0);
}

__device__ __forceinline__ float sigm(float x) {
    return __builtin_amdgcn_rcpf(1.f + __expf(-x));
}
__device__ __forceinline__ float ftanh(float x) {
    float a = __expf(-2.f * fabsf(x));
    float t = (1.f - a) * __builtin_amdgcn_rcpf(1.f + a);
    return copysignf(t, x);
}

// ---- pack weights to fp16 [dir][col(256)][k(384)] + zero the zero-page ----
__global__ __launch_bounds__(256) void pack_weights(
    const float* __restrict__ Wi_u, const float* __restrict__ Ui_u,
    const float* __restrict__ Wf_u, const float* __restrict__ Uf_u,
    const float* __restrict__ Wi_d, const float* __restrict__ Ui_d,
    const float* __restrict__ Wf_d, const float* __restrict__ Uf_d,
    _Float16* __restrict__ Bt, _Float16* __restrict__ zp)
{
    int idx = blockIdx.x * 256 + threadIdx.x;   // 2*256*384 = 196608 total
    if (idx < 512) zp[idx] = (_Float16)0.f;
    int d   = idx / 98304;
    int rem = idx % 98304;
    int col = rem / 384;
    int k   = rem % 384;
    const float* Wi = d ? Wi_d : Wi_u;
    const float* Ui = d ? Ui_d : Ui_u;
    const float* Wf = d ? Wf_d : Wf_u;
    const float* Uf = d ? Uf_d : Uf_u;
    float v;
    if (col < 192) v = (k < 320) ? Wi[k * 192 + col] : Ui[(k - 320) * 192 + col];
    else {
        int c = col - 192;
        v = (k < 320) ? Wf[k * 64 + c] : Uf[(k - 320) * 64 + c];
    }
    Bt[idx] = (_Float16)v;
}

// ---- fuse+convert embeddings to fp16 x16[B*T][320] ----
__global__ __launch_bounds__(256) void build_x16(
    const float* __restrict__ tok, const float* __restrict__ oh,
    const float* __restrict__ dep, _Float16* __restrict__ x16)
{
    int idx = blockIdx.x * 256 + threadIdx.x;   // 16384 bt * 40 granules
    int bt = idx / 40, g = idx % 40;
    const float* src = (g < 32) ? tok + (size_t)bt * 256 + g * 8
                     : (g < 36) ? oh  + (size_t)bt * 32 + (g - 32) * 8
                                : dep + (size_t)bt * 32 + (g - 36) * 8;
    float4 f0 = *(const float4*)src;
    float4 f1 = *(const float4*)(src + 4);
    f16x8 v;
    v[0] = (_Float16)f0.x; v[1] = (_Float16)f0.y;
    v[2] = (_Float16)f0.z; v[3] = (_Float16)f0.w;
    v[4] = (_Float16)f1.x; v[5] = (_Float16)f1.y;
    v[6] = (_Float16)f1.z; v[7] = (_Float16)f1.w;
    *(f16x8*)(x16 + (size_t)bt * 320 + g * 8) = v;
}

// ---- one fused level: up-side blocks [0,up_blocks), down-side the rest ----
__global__ __launch_bounds__(256, 2) void fused_level(
    const _Float16* __restrict__ x16,
    const int* __restrict__ nb, const int* __restrict__ nt,
    const _Float16* __restrict__ zp,
    float* __restrict__ out,
    int up_blocks, Side up, Side dn)
{
    __shared__ _Float16 At[128 * 64];            // 16 KB, [row][64k] swizzled
    __shared__ _Float16 Btl[256 * 64];           // 32 KB, [col][64k] swizzled
    __shared__ const _Float16* ld_xb[128];
    __shared__ const _Float16* ld_hb[128];

    const bool isup = (int)blockIdx.x < up_blocks;
    const Side S = isup ? up : dn;
    const int rowbase = (isup ? blockIdx.x : blockIdx.x - up_blocks) * 128;
    const int tid = threadIdx.x, lane = tid & 63, w = tid >> 6;
    const int l15 = lane & 15, qd = lane >> 4;
    const int rp_mask = (1 << S.rp_shift) - 1;

    if (tid < 128) {
        int grow = rowbase + tid;
        int pair = grow >> S.rp_shift;
        int slot = grow & rp_mask;
        int ps = slot==0?S.pos.x : slot==1?S.pos.y : slot==2?S.pos.z : S.pos.w;
        int hp = slot==0?S.hpos.x: slot==1?S.hpos.y: slot==2?S.hpos.z: S.hpos.w;
        bool zx = S.is_root && (slot == 3);
        int node = pair * 16 + ps;
        ld_xb[tid] = zx ? zp : x16 + ((size_t)nb[node] * 512 + nt[node]) * 320;
        ld_hb[tid] = (hp < 0) ? zp : S.h + (size_t)(pair * 16 + hp) * 64;
    }
    __syncthreads();

    // per-lane staging constants: lane -> (row sub, phys granule slot p)
    const int rsub = lane >> 3, p = lane & 7;
    const int koff = ((p - rsub) & 7) * 8;       // logical granule offset (fp16)
    const _Float16* axb[4];
    const _Float16* ahb[4];
    #pragma unroll
    for (int is = 0; is < 4; ++is) {
        int r = w * 32 + is * 8 + rsub;
        axb[is] = ld_xb[r] + koff;
        ahb[is] = ld_hb[r] + koff;
    }
    const _Float16* Bbase = S.B + (size_t)(w * 64 + rsub) * 384 + koff;

    f32x4 acc[8][4];
    #pragma unroll
    for (int i = 0; i < 8; ++i)
        #pragma unroll
        for (int j = 0; j < 4; ++j)
            acc[i][j] = (f32x4){0.f, 0.f, 0.f, 0.f};

    #pragma unroll
    for (int kt = 0; kt < 6; ++kt) {
        // A: 4 issues/wave (rows w*32..w*32+31), kt<5 from x16, kt=5 from h
        #pragma unroll
        for (int is = 0; is < 4; ++is) {
            const _Float16* g = (kt < 5) ? (axb[is] + kt * 64) : ahb[is];
            async16(g, &At[(w * 32 + is * 8) * 64]);
        }
        // B: 8 issues/wave (cols w*64..w*64+63)
        #pragma unroll
        for (int is = 0; is < 8; ++is)
            async16(Bbase + (size_t)is * 8 * 384 + kt * 64,
                    &Btl[(w * 64 + is * 8) * 64]);
        __syncthreads();

        #pragma unroll
        for (int s = 0; s < 2; ++s) {
            const int g0 = s * 4 + qd;           // logical granule wanted
            f16x8 af[8];
            #pragma unroll
            for (int i = 0; i < 8; ++i) {
                int R = i * 16 + l15;
                af[i] = *(const f16x8*)&At[R * 64 + ((g0 + R) & 7) * 8];
            }
            #pragma unroll
            for (int j = 0; j < 4; ++j) {
                int C = j * 64 + w * 16 + l15;
                f16x8 bf = *(const f16x8*)&Btl[C * 64 + ((g0 + C) & 7) * 8];
                #pragma unroll
                for (int i = 0; i < 8; ++i)
                    acc[i][j] = __builtin_amdgcn_mfma_f32_16x16x32_f16(
                        af[i], bf, acc[i][j], 0, 0, 0);
            }
        }
        __syncthreads();
    }

    // ---- epilogue: lane owns i/o/u/f at hidden col colj = w*16+l15 ----
    const int colj = w * 16 + l15;
    const float bi = S.b_iou[colj], bo = S.b_iou[64 + colj],
                bu = S.b_iou[128 + colj], bff = S.b_f[colj];

    if (!S.is_root) {
        #pragma unroll
        for (int i = 0; i < 8; ++i) {
            #pragma unroll
            for (int r = 0; r < 4; ++r) {
                int R = i * 16 + qd * 4 + r;
                int grow = rowbase + R;
                int pair = grow >> S.rp_shift;
                int slot = grow & rp_mask;
                int hp = slot==0?S.hpos.x: slot==1?S.hpos.y
                       : slot==2?S.hpos.z: S.hpos.w;
                float I = acc[i][0][r] + bi;
                float O = acc[i][1][r] + bo;
                float U = acc[i][2][r] + bu;
                float F = acc[i][3][r] + bff;
                float cin = (hp >= 0)
                    ? (float)S.c[(size_t)(pair * 16 + hp) * 64 + colj] : 0.f;
                float cn = sigm(I) * ftanh(U) + sigm(F) * cin;
                float h  = sigm(O) * ftanh(cn);
                int oc = slot==0?S.ocol.x: slot==1?S.ocol.y
                       : slot==2?S.ocol.z: S.ocol.w;
                if (oc >= 0) {
                    out[(size_t)pair * 192 + oc + colj] = h;
                } else {
                    int ps = slot==0?S.pos.x: slot==1?S.pos.y
                           : slot==2?S.pos.z: S.pos.w;
                    size_t nd = (size_t)(pair * 16 + ps) * 64 + colj;
                    S.h[nd] = (_Float16)h;
                    S.c[nd] = (_Float16)cn;
                }
            }
        }
    } else {
        // 4 rows/pair: r0=[x||h7], r1=[x||h9], r2=[x||0], r3=zeros
        #pragma unroll
        for (int i = 0; i < 8; ++i) {
            int R = i * 16 + qd * 4;
            int pair = (rowbase + R) >> 2;
            float I  = acc[i][0][0] + acc[i][0][1] - acc[i][0][2] + bi;
            float O  = acc[i][1][0] + acc[i][1][1] - acc[i][1][2] + bo;
            float U  = acc[i][2][0] + acc[i][2][1] - acc[i][2][2] + bu;
            float F7 = acc[i][3][0] + bff;
            float F9 = acc[i][3][1] + bff;
            float c7 = (float)S.c[(size_t)(pair * 16 + 7) * 64 + colj];
            float c9 = (float)S.c[(size_t)(pair * 16 + 9) * 64 + colj];
            float cn = sigm(I) * ftanh(U) + sigm(F7) * c7 + sigm(F9) * c9;
            float h  = sigm(O) * ftanh(cn);
            out[(size_t)pair * 192 + colj] = h;
        }
    }
}

extern "C" void kernel_launch(void* const* d_in, const int* in_sizes, int n_in,
                              void* d_out, int out_size, void* d_ws, size_t ws_size,
                              hipStream_t stream)
{
    const float* tok  = (const float*)d_in[0];
    const float* ohp  = (const float*)d_in[1];
    const float* dep  = (const float*)d_in[2];
    const int*   nb   = (const int*)d_in[3];
    const int*   nt   = (const int*)d_in[4];
    const float* Wi_u = (const float*)d_in[13];
    const float* Ui_u = (const float*)d_in[14];
    const float* bi_u = (const float*)d_in[15];
    const float* Wf_u = (const float*)d_in[16];
    const float* Uf_u = (const float*)d_in[17];
    const float* bf_u = (const float*)d_in[18];
    const float* Wi_d = (const float*)d_in[19];
    const float* Ui_d = (const float*)d_in[20];
    const float* bi_d = (const float*)d_in[21];
    const float* Wf_d = (const float*)d_in[22];
    const float* Uf_d = (const float*)d_in[23];
    const float* bf_d = (const float*)d_in[24];

    char* ws = (char*)d_ws;
    _Float16* Bt   = (_Float16*)(ws);                          // 384 KB
    _Float16* zp   = (_Float16*)(ws + (512 << 10));            // 1 KB zero page
    _Float16* x16  = (_Float16*)(ws + (1  << 20));             // 10.5 MB
    _Float16* h_u  = (_Float16*)(ws + (16 << 20));             // 32 MB
    _Float16* c_u  = (_Float16*)(ws + (48 << 20));             // 32 MB
    _Float16* h_d  = (_Float16*)(ws + (80 << 20));             // 32 MB
    _Float16* c_d  = (_Float16*)(ws + (112 << 20));            // 32 MB
    float* out = (float*)d_out;

    pack_weights<<<768, 256, 0, stream>>>(Wi_u, Ui_u, Wf_u, Uf_u,
                                          Wi_d, Ui_d, Wf_d, Uf_d, Bt, zp);
    build_x16<<<2560, 256, 0, stream>>>(tok, ohp, dep, x16);

    const _Float16* Bu = Bt;
    const _Float16* Bd = Bt + 98304;
    int4 none = {-1, -1, -1, -1};

    // L0: up {pos 0,15, no h} + down {pos 8, no h}
    {
        Side U = {Bu, bi_u, bf_u, h_u, c_u, 1, 0, {0, 15, 0, 0}, none, none};
        Side D = {Bd, bi_d, bf_d, h_d, c_d, 0, 0, {8, 0, 0, 0}, none, none};
        fused_level<<<384, 256, 0, stream>>>(x16, nb, nt, zp, out, 256, U, D);
    }
    // L1..L6
    for (int t = 1; t <= 6; ++t) {
        Side U = {Bu, bi_u, bf_u, h_u, c_u, 1, 0,
                  {t, 15 - t, 0, 0}, {t - 1, 16 - t, -1, -1}, none};
        Side D = {Bd, bi_d, bf_d, h_d, c_d, 1, 0,
                  {8 - t, 8 + t, 0, 0}, {9 - t, 7 + t, -1, -1}, none};
        fused_level<<<512, 256, 0, stream>>>(x16, nb, nt, zp, out, 256, U, D);
    }
    // L7: up {pos 7} + down {pos 1 -> state, pos 15 -> out[128..191]}
    {
        Side U = {Bu, bi_u, bf_u, h_u, c_u, 0, 0,
                  {7, 0, 0, 0}, {6, -1, -1, -1}, none};
        Side D = {Bd, bi_d, bf_d, h_d, c_d, 1, 0,
                  {1, 15, 0, 0}, {2, 14, -1, -1}, {-1, 128, -1, -1}};
        fused_level<<<384, 256, 0, stream>>>(x16, nb, nt, zp, out, 128, U, D);
    }
    // L8: up root (4 rows/pair -> out[0..63]) + down {pos 0 -> out[64..127]}
    {
        Side U = {Bu, bi_u, bf_u, h_u, c_u, 2, 1,
                  {8, 8, 8, 8}, {7, 9, -1, -1}, {0, 0, 0, 0}};
        Side D = {Bd, bi_d, bf_d, h_d, c_d, 0, 0,
                  {0, 0, 0, 0}, {1, -1, -1, -1}, {64, -1, -1, -1}};
        fused_level<<<640, 256, 0, stream>>>(x16, nb, nt, zp, out, 512, U, D);
    }
    (void)in_sizes; (void)n_in; (void)out_size; (void)ws_size;
}